// Round 1
// baseline (1740.411 us; speedup 1.0000x reference)
//
#include <hip/hip_runtime.h>
#include <cstdint>
#include <cstddef>

// R0: single persistent kernel. 256 WGs x 256 threads, 2 batch rows per WG
// (rows are independent given precomputed td[] and noise z[]).
// - All weights (Wih,Whh,dW1,dW2,gW1,gW2) packed f16 in VGPRs (~288/thread).
// - h / x / activations broadcast via LDS (wave-uniform b128 reads).
// - MACs via v_dot2_f32_f16 (f32 accumulate), k-split over lane halves for the
//   384x128 gh/gi matvecs (shfl_xor(32) combine).
// - Exact jax threefry2x32 (fold_in + partitionable random_bits) + Giles erfinv
//   noise, precomputed into LDS per WG.
// Predicted: ~300-500us, MfmaUtil 0, VALUBusy 40-60%, 1 WG/CU.

typedef _Float16 f16;
typedef _Float16 f16x2 __attribute__((ext_vector_type(2)));

#define NSTEP 127
#define NSUB 10
#define B_LEN 512
#define S_LEN 128
#define H_LEN 128

__device__ __forceinline__ float dot2acc(f16x2 a, f16x2 b, float c) {
#if __has_builtin(__builtin_amdgcn_fdot2)
  return __builtin_amdgcn_fdot2(a, b, c, false);
#else
  return c + (float)a[0] * (float)b[0] + (float)a[1] * (float)b[1];
#endif
}

__device__ __forceinline__ f16x2 bchalf(unsigned int u) {
  return __builtin_bit_cast(f16x2, u);
}

#define DOT4R(acc, wr, base, dv)                              \
  do {                                                        \
    acc = dot2acc((wr)[(base) + 0], bchalf((dv).x), acc);     \
    acc = dot2acc((wr)[(base) + 1], bchalf((dv).y), acc);     \
    acc = dot2acc((wr)[(base) + 2], bchalf((dv).z), acc);     \
    acc = dot2acc((wr)[(base) + 3], bchalf((dv).w), acc);     \
  } while (0)

// JAX threefry2x32 (20 rounds, rolled schedule) -- bit-exact.
__device__ __forceinline__ void tf2x32(unsigned int k0, unsigned int k1,
                                       unsigned int& x0, unsigned int& x1) {
  unsigned int ks[3] = {k0, k1, k0 ^ k1 ^ 0x1BD11BDAu};
  x0 += ks[0];
  x1 += ks[1];
  const int R[2][4] = {{13, 15, 26, 6}, {17, 29, 16, 24}};
#pragma unroll
  for (int g = 0; g < 5; ++g) {
#pragma unroll
    for (int j = 0; j < 4; ++j) {
      const int r = R[g & 1][j];
      x0 += x1;
      x1 = (x1 << r) | (x1 >> (32 - r));
      x1 ^= x0;
    }
    x0 += ks[(g + 1) % 3];
    x1 += ks[(g + 2) % 3] + (unsigned int)(g + 1);
  }
}

// XLA f32 ErfInv (Giles 2012 polynomial) -- matches lax.erf_inv closely.
__device__ __forceinline__ float erfinv_f32(float x) {
  float w = -log1pf(-x * x);
  float p;
  if (w < 5.0f) {
    w = w - 2.5f;
    p = 2.81022636e-08f;
    p = fmaf(p, w, 3.43273939e-07f);
    p = fmaf(p, w, -3.5233877e-06f);
    p = fmaf(p, w, -4.39150654e-06f);
    p = fmaf(p, w, 0.00021858087f);
    p = fmaf(p, w, -0.00125372503f);
    p = fmaf(p, w, -0.00417768164f);
    p = fmaf(p, w, 0.246640727f);
    p = fmaf(p, w, 1.50140941f);
  } else {
    w = sqrtf(w) - 3.0f;
    p = -0.000200214257f;
    p = fmaf(p, w, 0.000100950558f);
    p = fmaf(p, w, 0.00134934322f);
    p = fmaf(p, w, -0.00367342844f);
    p = fmaf(p, w, 0.00573950773f);
    p = fmaf(p, w, -0.0076224613f);
    p = fmaf(p, w, 0.00943887047f);
    p = fmaf(p, w, 1.00167406f);
    p = fmaf(p, w, 2.83297682f);
  }
  return p * x;
}

__global__ __launch_bounds__(256, 1) void sde_fused_kernel(
    const float* __restrict__ inputs, const float* __restrict__ times,
    const int* __restrict__ non_zero, const float* __restrict__ Wih,
    const float* __restrict__ Whh, const float* __restrict__ bih,
    const float* __restrict__ bhh, const float* __restrict__ dW1,
    const float* __restrict__ db1, const float* __restrict__ dW2,
    const float* __restrict__ db2, const float* __restrict__ gW1,
    const float* __restrict__ gb1, const float* __restrict__ gW2,
    const float* __restrict__ gb2, float* __restrict__ out) {
  __shared__ float sZ[NSTEP * NSUB * 2];
  __shared__ float sTd[NSTEP];
  __shared__ float sDt[NSTEP];
  __shared__ float sSq[NSTEP];
  __shared__ float sU[NSTEP];
  __shared__ __align__(16) f16 sX[2][H_LEN];
  __shared__ __align__(16) f16 sH2[2][H_LEN];
  __shared__ __align__(16) f16 sH[2][H_LEN];
  __shared__ __align__(16) f16 sAct[2][H_LEN];

  const int t = threadIdx.x;
  const int w = t >> 6;
  const int l = t & 63;
  const int wg = blockIdx.x;

  const int oq = w * 32 + (l & 31);  // output/element index 0..127
  const int kh = l >> 5;             // k-half (gh/gi/L1 split), also my ROW
  const int kbase = kh * 64;
  const int ROW = kh;
  const int E = oq;

  const int b0 = wg * 2;
  const int La = non_zero[b0] - 1;
  const int Lb = non_zero[b0 + 1] - 1;
  const int Lmax = (La > Lb) ? La : Lb;
  const int myb = b0 + ROW;
  const int Lown = non_zero[myb] - 1;

  // ---- td / dt / sq precompute (same for every WG; input-only)
  if (t < NSTEP) {
    const int i = t;
    float s1 = 0.f, s2 = 0.f;
    int cnt = 0;
    for (int b = 0; b < B_LEN; ++b) {
      const int nzb = non_zero[b];
      const float tip1 = times[b * S_LEN + i + 1];
      const bool valid = (i < nzb - 1) && (tip1 != 0.0f);
      if (valid) {
        cnt += 1;
        s1 += times[b * S_LEN + i];
        s2 += tip1;
      }
    }
    const float cntf = (float)((cnt < 1) ? 1 : cnt);
    const float ts = s1 / cntf * 0.02f;
    const float te = s2 / cntf * 0.02f;
    const float td = (te == ts) ? 1.0f : (te - ts);
    sTd[i] = td;
    const float dtv = td / 10.0f;
    sDt[i] = dtv;
    sSq[i] = sqrtf(dtv);
  }

  // ---- noise precompute: z[i][s][row] for this WG's two rows
  for (int idx = t; idx < NSTEP * NSUB * 2; idx += 256) {
    const int r = idx & 1;
    const int is = idx >> 1;  // i*10+s
    unsigned int f0 = 0u, f1 = (unsigned int)is;
    tf2x32(0u, 42u, f0, f1);  // fold_in(key(42), i*10+s)
    unsigned int y0 = 0u, y1 = (unsigned int)(b0 + r);
    tf2x32(f0, f1, y0, y1);   // partitionable counter (0, b)
    const unsigned int bits = y1;  // low 32 of (o0<<32|o1)
    const float fl = __uint_as_float((bits >> 9) | 0x3F800000u) - 1.0f;
    const float lo = __uint_as_float(0xBF7FFFFFu);  // nextafter(-1,0)
    float u = fl * (1.0f - lo) + lo;
    u = fmaxf(lo, u);
    sZ[idx] = 1.41421356237f * erfinv_f32(u);
  }
  __syncthreads();
  if (t >= 1 && t < NSTEP) sU[t] = expf(-sTd[t - 1]);
  if (t == 0) sU[0] = 1.0f;

  // ---- register weight preload (packed f16)
  f16x2 rWih[3][32], rWhh[3][32];
#pragma unroll
  for (int j = 0; j < 3; ++j) {
    const float* pi = Wih + (size_t)(oq + 128 * j) * 128 + kbase;
    const float* ph = Whh + (size_t)(oq + 128 * j) * 128 + kbase;
#pragma unroll
    for (int c = 0; c < 32; ++c) {
      f16x2 a;
      a[0] = (f16)pi[2 * c];
      a[1] = (f16)pi[2 * c + 1];
      rWih[j][c] = a;
      f16x2 b;
      b[0] = (f16)ph[2 * c];
      b[1] = (f16)ph[2 * c + 1];
      rWhh[j][c] = b;
    }
  }
  f16x2 rW1[32];
  {
    const float* p1 = (oq < 64) ? (dW1 + (size_t)oq * 128 + kbase)
                                : (gW1 + (size_t)(oq - 64) * 128 + kbase);
#pragma unroll
    for (int c = 0; c < 32; ++c) {
      f16x2 a;
      a[0] = (f16)p1[2 * c];
      a[1] = (f16)p1[2 * c + 1];
      rW1[c] = a;
    }
  }
  const float bias1 = (oq < 64) ? db1[oq] : gb1[oq - 64];
  f16x2 rW2d[32], rW2g[32];
  {
    const float* pd = dW2 + (size_t)E * 64;
    const float* pg = gW2 + (size_t)E * 64;
#pragma unroll
    for (int c = 0; c < 32; ++c) {
      f16x2 a;
      a[0] = (f16)pd[2 * c];
      a[1] = (f16)pd[2 * c + 1];
      rW2d[c] = a;
      f16x2 b;
      b[0] = (f16)pg[2 * c];
      b[1] = (f16)pg[2 * c + 1];
      rW2g[c] = b;
    }
  }
  const float bias2d = db2[E], bias2g = gb2[E];
  const float rB0 = bih[oq] + bhh[oq];
  const float rB1 = bih[oq + 128] + bhh[oq + 128];
  const float rBi2 = bih[oq + 256];
  const float rBh2 = bhh[oq + 256];

  // ---- state init
  float h2e = 0.f, h1e = 0.f;
  sH2[ROW][E] = (f16)0.f;

  const int xr = t >> 7;  // 0/1 row for x staging
  const int xe = t & 127;
  const float* xbase = inputs + (size_t)(b0 + xr) * H_LEN + xe;
  const size_t xstride = (size_t)B_LEN * H_LEN;
  float xreg = xbase[0];

  for (int i = 0; i < Lmax; ++i) {
    sX[xr][xe] = (f16)xreg;
    __syncthreads();  // publish sX + sH2
    if (i + 1 < NSTEP) xreg = xbase[(size_t)(i + 1) * xstride];

    // ---- gh + gi matvecs (ksplit over lane halves)
    float ai00 = 0.f, ai01 = 0.f, ai10 = 0.f, ai11 = 0.f, ai20 = 0.f,
          ai21 = 0.f;
    float ah00 = 0.f, ah01 = 0.f, ah10 = 0.f, ah11 = 0.f, ah20 = 0.f,
          ah21 = 0.f;
#pragma unroll
    for (int c = 0; c < 8; ++c) {
      const int cg = (kh << 3) + c;
      const uint4 xv0 = *(const uint4*)&sX[0][cg * 8];
      const uint4 xv1 = *(const uint4*)&sX[1][cg * 8];
      const uint4 hv0 = *(const uint4*)&sH2[0][cg * 8];
      const uint4 hv1 = *(const uint4*)&sH2[1][cg * 8];
      DOT4R(ai00, rWih[0], c * 4, xv0);
      DOT4R(ai01, rWih[0], c * 4, xv1);
      DOT4R(ai10, rWih[1], c * 4, xv0);
      DOT4R(ai11, rWih[1], c * 4, xv1);
      DOT4R(ai20, rWih[2], c * 4, xv0);
      DOT4R(ai21, rWih[2], c * 4, xv1);
      DOT4R(ah00, rWhh[0], c * 4, hv0);
      DOT4R(ah01, rWhh[0], c * 4, hv1);
      DOT4R(ah10, rWhh[1], c * 4, hv0);
      DOT4R(ah11, rWhh[1], c * 4, hv1);
      DOT4R(ah20, rWhh[2], c * 4, hv0);
      DOT4R(ah21, rWhh[2], c * 4, hv1);
    }
    // combine k-halves: r/z gates can sum gi+gh first; n needs them separate
    float s00 = ai00 + ah00;
    s00 += __shfl_xor(s00, 32);
    float s01 = ai01 + ah01;
    s01 += __shfl_xor(s01, 32);
    float s10 = ai10 + ah10;
    s10 += __shfl_xor(s10, 32);
    float s11 = ai11 + ah11;
    s11 += __shfl_xor(s11, 32);
    ai20 += __shfl_xor(ai20, 32);
    ai21 += __shfl_xor(ai21, 32);
    ah20 += __shfl_xor(ah20, 32);
    ah21 += __shfl_xor(ah21, 32);

    // ---- GRU for (ROW, E) -- this thread owns it
    const float sr = ROW ? s01 : s00;
    const float sz = ROW ? s11 : s10;
    const float inn = ROW ? ai21 : ai20;
    const float hnn = ROW ? ah21 : ah20;
    const float rg = 1.0f / (1.0f + expf(-(sr + rB0)));
    const float zg = 1.0f / (1.0f + expf(-(sz + rB1)));
    const float nn = tanhf(inn + rBi2 + rg * (hnn + rBh2));
    const float hg = (1.0f - zg) * nn + zg * h2e;
    float hh = hg;
    sH[ROW][E] = (f16)hg;
    __syncthreads();

    // ---- 10 Euler-Maruyama substeps
    const float dt = sDt[i];
    const float sq = sSq[i];
    const float* zrow = &sZ[(i * NSUB) * 2];
    for (int s = 0; s < NSUB; ++s) {
      // L1: a[o]=tanh-pre (o<64, drift) / softplus-pre (o>=64, diff), both rows
      float a0 = 0.f, a1 = 0.f;
#pragma unroll
      for (int c = 0; c < 8; ++c) {
        const uint4 hv0 = *(const uint4*)&sH[0][kbase + c * 8];
        const uint4 hv1 = *(const uint4*)&sH[1][kbase + c * 8];
        DOT4R(a0, rW1, c * 4, hv0);
        DOT4R(a1, rW1, c * 4, hv1);
      }
      a0 += __shfl_xor(a0, 32);
      a1 += __shfl_xor(a1, 32);
      const float av = (kh ? a1 : a0) + bias1;
      const float act = (oq < 64)
                            ? tanhf(av)
                            : (fmaxf(av, 0.f) + log1pf(expf(-fabsf(av))));
      sAct[kh][oq] = (f16)act;
      __syncthreads();
      // L2: f[E], g[E] for my row; update my hh
      float fa = 0.f, ga = 0.f;
#pragma unroll
      for (int c = 0; c < 8; ++c) {
        const uint4 tv = *(const uint4*)&sAct[ROW][c * 8];
        const uint4 sv = *(const uint4*)&sAct[ROW][64 + c * 8];
        DOT4R(fa, rW2d, c * 4, tv);
        DOT4R(ga, rW2g, c * 4, sv);
      }
      fa += bias2d;
      ga += bias2g;
      const float zz = zrow[s * 2 + ROW];
      hh = hh + fa * dt + ga * (sq * zz);
      sH[ROW][E] = (f16)hh;
      __syncthreads();
    }

    // ---- h1/h2 update (frozen once row is done; output = last valid h2)
    if (i < Lown) {
      if (i == 0) {
        h2e = hg;
      } else {
        const float uu = sU[i];
        h2e = uu * hg + (1.0f - uu) * h1e;
      }
      h1e = hh;
    }
    sH2[ROW][E] = (f16)h2e;
  }

  out[(size_t)myb * H_LEN + E] = h2e;
}

extern "C" void kernel_launch(void* const* d_in, const int* in_sizes, int n_in,
                              void* d_out, int out_size, void* d_ws,
                              size_t ws_size, hipStream_t stream) {
  (void)in_sizes;
  (void)n_in;
  (void)out_size;
  (void)d_ws;
  (void)ws_size;
  const float* inputs = (const float*)d_in[0];
  const float* times = (const float*)d_in[1];
  const int* non_zero = (const int*)d_in[2];
  const float* Wih = (const float*)d_in[3];
  const float* Whh = (const float*)d_in[4];
  const float* bih = (const float*)d_in[5];
  const float* bhh = (const float*)d_in[6];
  const float* dW1 = (const float*)d_in[7];
  const float* db1 = (const float*)d_in[8];
  const float* dW2 = (const float*)d_in[9];
  const float* db2 = (const float*)d_in[10];
  const float* gW1 = (const float*)d_in[11];
  const float* gb1 = (const float*)d_in[12];
  const float* gW2 = (const float*)d_in[13];
  const float* gb2 = (const float*)d_in[14];
  float* out = (float*)d_out;
  hipLaunchKernelGGL(sde_fused_kernel, dim3(256), dim3(256), 0, stream, inputs,
                     times, non_zero, Wih, Whh, bih, bhh, dW1, db1, dW2, db2,
                     gW1, gb1, gW2, gb2, out);
}

// Round 2
// 1388.345 us; speedup vs baseline: 1.2536x; 1.2536x over previous
//
#include <hip/hip_runtime.h>
#include <cstdint>
#include <cstddef>

// R1: 256 WGs x 512 threads, 2 rows/WG, k-split 4 (kq = t&3, oq = t>>2).
// - Weight regs/thread halved vs R0 (128 f16x2) -> ~200 VGPR -> 2 waves/SIMD.
// - k-reduce via shfl_xor(1/2) = DPP quad_perm (cheap, in-VALU).
// - td precompute moved to a separate 127-block kernel (writes d_ws).
// - native exp/log/rcp activations in the hot loop.
// Predicted: ~700-900us, VALUBusy 35-45%, Occupancy ~17%.

typedef _Float16 f16;
typedef _Float16 f16x2 __attribute__((ext_vector_type(2)));

#define NSTEP 127
#define NSUB 10
#define B_LEN 512
#define S_LEN 128
#define H_LEN 128

__device__ __forceinline__ float dot2acc(f16x2 a, f16x2 b, float c) {
  return __builtin_amdgcn_fdot2(a, b, c, false);
}
__device__ __forceinline__ f16x2 bchalf(unsigned int u) {
  return __builtin_bit_cast(f16x2, u);
}

#define DOT4R(acc, wr, base, dv)                          \
  do {                                                    \
    acc = dot2acc((wr)[(base) + 0], bchalf((dv).x), acc); \
    acc = dot2acc((wr)[(base) + 1], bchalf((dv).y), acc); \
    acc = dot2acc((wr)[(base) + 2], bchalf((dv).z), acc); \
    acc = dot2acc((wr)[(base) + 3], bchalf((dv).w), acc); \
  } while (0)

// JAX threefry2x32 (20 rounds) -- bit-exact (verified R0: absmax 9.8e-4).
__device__ __forceinline__ void tf2x32(unsigned int k0, unsigned int k1,
                                       unsigned int& x0, unsigned int& x1) {
  unsigned int ks[3] = {k0, k1, k0 ^ k1 ^ 0x1BD11BDAu};
  x0 += ks[0];
  x1 += ks[1];
  const int R[2][4] = {{13, 15, 26, 6}, {17, 29, 16, 24}};
#pragma unroll
  for (int g = 0; g < 5; ++g) {
#pragma unroll
    for (int j = 0; j < 4; ++j) {
      const int r = R[g & 1][j];
      x0 += x1;
      x1 = (x1 << r) | (x1 >> (32 - r));
      x1 ^= x0;
    }
    x0 += ks[(g + 1) % 3];
    x1 += ks[(g + 2) % 3] + (unsigned int)(g + 1);
  }
}

__device__ __forceinline__ float erfinv_f32(float x) {
  float w = -log1pf(-x * x);
  float p;
  if (w < 5.0f) {
    w = w - 2.5f;
    p = 2.81022636e-08f;
    p = fmaf(p, w, 3.43273939e-07f);
    p = fmaf(p, w, -3.5233877e-06f);
    p = fmaf(p, w, -4.39150654e-06f);
    p = fmaf(p, w, 0.00021858087f);
    p = fmaf(p, w, -0.00125372503f);
    p = fmaf(p, w, -0.00417768164f);
    p = fmaf(p, w, 0.246640727f);
    p = fmaf(p, w, 1.50140941f);
  } else {
    w = sqrtf(w) - 3.0f;
    p = -0.000200214257f;
    p = fmaf(p, w, 0.000100950558f);
    p = fmaf(p, w, 0.00134934322f);
    p = fmaf(p, w, -0.00367342844f);
    p = fmaf(p, w, 0.00573950773f);
    p = fmaf(p, w, -0.0076224613f);
    p = fmaf(p, w, 0.00943887047f);
    p = fmaf(p, w, 1.00167406f);
    p = fmaf(p, w, 2.83297682f);
  }
  return p * x;
}

// fast activations (native v_exp/v_log/v_rcp; errors ~1e-6 << 6.2e-3 threshold)
__device__ __forceinline__ float frcp(float x) {
  return __builtin_amdgcn_rcpf(x);
}
__device__ __forceinline__ float fsig(float x) {
  return frcp(1.0f + __expf(-x));
}
__device__ __forceinline__ float ftanh_fast(float x) {
  return 1.0f - 2.0f * frcp(__expf(2.0f * x) + 1.0f);
}
__device__ __forceinline__ float fsoftplus(float x) {
  return fmaxf(x, 0.0f) + __logf(1.0f + __expf(-fabsf(x)));
}

// ---- td precompute: one block per step i; writes wsTd[i]
__global__ __launch_bounds__(256) void td_kernel(
    const float* __restrict__ times, const int* __restrict__ non_zero,
    float* __restrict__ wsTd) {
  __shared__ float sA[256], sB[256];
  __shared__ int sC[256];
  const int i = blockIdx.x;
  const int t = threadIdx.x;
  float s1 = 0.f, s2 = 0.f;
  int c = 0;
  for (int b = t; b < B_LEN; b += 256) {
    const int nz = non_zero[b];
    const float t1 = times[b * S_LEN + i + 1];
    const bool v = (i < nz - 1) && (t1 != 0.0f);
    if (v) {
      c += 1;
      s1 += times[b * S_LEN + i];
      s2 += t1;
    }
  }
  sA[t] = s1;
  sB[t] = s2;
  sC[t] = c;
  __syncthreads();
  for (int o = 128; o > 0; o >>= 1) {
    if (t < o) {
      sA[t] += sA[t + o];
      sB[t] += sB[t + o];
      sC[t] += sC[t + o];
    }
    __syncthreads();
  }
  if (t == 0) {
    const float cnt = (float)((sC[0] < 1) ? 1 : sC[0]);
    const float ts = sA[0] / cnt * 0.02f;
    const float te = sB[0] / cnt * 0.02f;
    wsTd[i] = (te == ts) ? 1.0f : (te - ts);
  }
}

__global__ __launch_bounds__(512, 2) void sde_fused_kernel(
    const float* __restrict__ inputs, const int* __restrict__ non_zero,
    const float* __restrict__ Wih, const float* __restrict__ Whh,
    const float* __restrict__ bih, const float* __restrict__ bhh,
    const float* __restrict__ dW1, const float* __restrict__ db1,
    const float* __restrict__ dW2, const float* __restrict__ db2,
    const float* __restrict__ gW1, const float* __restrict__ gb1,
    const float* __restrict__ gW2, const float* __restrict__ gb2,
    const float* __restrict__ wsTd, float* __restrict__ out) {
  __shared__ float sZ[NSTEP * NSUB * 2];
  __shared__ float sDt[NSTEP], sSq[NSTEP], sU[NSTEP];
  __shared__ __align__(16) f16 sX[2][H_LEN];
  __shared__ __align__(16) f16 sH2[2][H_LEN];
  __shared__ __align__(16) f16 sH[2][H_LEN];
  __shared__ __align__(16) f16 sAct[2][H_LEN];

  const int t = threadIdx.x;
  const int kq = t & 3;    // k-quarter; reduce via shfl_xor 1,2 (quad DPP)
  const int oq = t >> 2;   // output index 0..127
  const int kb32 = kq * 32;
  const int kb16 = kq * 16;
  const int wg = blockIdx.x;
  const int b0 = wg * 2;

  const int La = non_zero[b0] - 1;
  const int Lb = non_zero[b0 + 1] - 1;
  const int Lmax = (La > Lb) ? La : Lb;

  // ---- noise precompute (identical bit-stream to R0)
  for (int idx = t; idx < NSTEP * NSUB * 2; idx += 512) {
    const int r = idx & 1;
    const int is = idx >> 1;
    unsigned int f0 = 0u, f1 = (unsigned int)is;
    tf2x32(0u, 42u, f0, f1);
    unsigned int y0 = 0u, y1 = (unsigned int)(b0 + r);
    tf2x32(f0, f1, y0, y1);
    const unsigned int bits = y1;
    const float fl = __uint_as_float((bits >> 9) | 0x3F800000u) - 1.0f;
    const float lo = __uint_as_float(0xBF7FFFFFu);
    float u = fl * (1.0f - lo) + lo;
    u = fmaxf(lo, u);
    sZ[idx] = 1.41421356237f * erfinv_f32(u);
  }
  if (t < NSTEP) {
    const float td = wsTd[t];
    sDt[t] = td * 0.1f;
    sSq[t] = sqrtf(td * 0.1f);
    sU[t] = (t == 0) ? 1.0f : __expf(-wsTd[t - 1]);
  }

  // ---- register weight preload (packed f16, k-quarter slices)
  f16x2 rWih[3][16], rWhh[3][16];
#pragma unroll
  for (int g = 0; g < 3; ++g) {
    const float* pi = Wih + (size_t)(oq + 128 * g) * 128 + kb32;
    const float* ph = Whh + (size_t)(oq + 128 * g) * 128 + kb32;
#pragma unroll
    for (int c = 0; c < 16; ++c) {
      f16x2 a;
      a[0] = (f16)pi[2 * c];
      a[1] = (f16)pi[2 * c + 1];
      rWih[g][c] = a;
      f16x2 b;
      b[0] = (f16)ph[2 * c];
      b[1] = (f16)ph[2 * c + 1];
      rWhh[g][c] = b;
    }
  }
  f16x2 rW1[16];
  {
    const float* p1 = (oq < 64) ? (dW1 + (size_t)oq * 128 + kb32)
                                : (gW1 + (size_t)(oq - 64) * 128 + kb32);
#pragma unroll
    for (int c = 0; c < 16; ++c) {
      f16x2 a;
      a[0] = (f16)p1[2 * c];
      a[1] = (f16)p1[2 * c + 1];
      rW1[c] = a;
    }
  }
  f16x2 rW2d[8], rW2g[8];
  {
    const float* pd = dW2 + (size_t)oq * 64 + kb16;
    const float* pg = gW2 + (size_t)oq * 64 + kb16;
#pragma unroll
    for (int c = 0; c < 8; ++c) {
      f16x2 a;
      a[0] = (f16)pd[2 * c];
      a[1] = (f16)pd[2 * c + 1];
      rW2d[c] = a;
      f16x2 b;
      b[0] = (f16)pg[2 * c];
      b[1] = (f16)pg[2 * c + 1];
      rW2g[c] = b;
    }
  }
  const float bias1 = (oq < 64) ? db1[oq] : gb1[oq - 64];
  const float bias2d = db2[oq], bias2g = gb2[oq];
  const float rB0 = bih[oq] + bhh[oq];
  const float rB1 = bih[oq + 128] + bhh[oq + 128];
  const float rBi2 = bih[oq + 256];
  const float rBh2 = bhh[oq + 256];

  // ---- state
  float h2e[2] = {0.f, 0.f}, h1e[2] = {0.f, 0.f};
  if (kq < 2) sH2[kq][oq] = (f16)0.f;

  const int xr = (t >> 7) & 1;
  const int xe = t & 127;
  const float* xbase = inputs + (size_t)(b0 + xr) * H_LEN + xe;
  const size_t xstride = (size_t)B_LEN * H_LEN;
  float xreg = (t < 256) ? xbase[0] : 0.f;

  __syncthreads();  // sZ, sDt/sSq/sU, sH2 init visible

  for (int i = 0; i < Lmax; ++i) {
    if (t < 256) sX[xr][xe] = (f16)xreg;
    __syncthreads();  // A: sX + sH2 visible
    if (t < 256 && (i + 1) < NSTEP) xreg = xbase[(size_t)(i + 1) * xstride];

    // ---- GRU matvecs: 12 accumulators, 16-dot2 chains each
    float ai0r0 = 0.f, ai0r1 = 0.f, ai1r0 = 0.f, ai1r1 = 0.f, ai2r0 = 0.f,
          ai2r1 = 0.f;
    float ah0r0 = 0.f, ah0r1 = 0.f, ah1r0 = 0.f, ah1r1 = 0.f, ah2r0 = 0.f,
          ah2r1 = 0.f;
#pragma unroll
    for (int c = 0; c < 4; ++c) {
      const uint4 xv0 = *(const uint4*)&sX[0][kb32 + c * 8];
      const uint4 xv1 = *(const uint4*)&sX[1][kb32 + c * 8];
      const uint4 hv0 = *(const uint4*)&sH2[0][kb32 + c * 8];
      const uint4 hv1 = *(const uint4*)&sH2[1][kb32 + c * 8];
      DOT4R(ai0r0, rWih[0], c * 4, xv0);
      DOT4R(ai0r1, rWih[0], c * 4, xv1);
      DOT4R(ai1r0, rWih[1], c * 4, xv0);
      DOT4R(ai1r1, rWih[1], c * 4, xv1);
      DOT4R(ai2r0, rWih[2], c * 4, xv0);
      DOT4R(ai2r1, rWih[2], c * 4, xv1);
      DOT4R(ah0r0, rWhh[0], c * 4, hv0);
      DOT4R(ah0r1, rWhh[0], c * 4, hv1);
      DOT4R(ah1r0, rWhh[1], c * 4, hv0);
      DOT4R(ah1r1, rWhh[1], c * 4, hv1);
      DOT4R(ah2r0, rWhh[2], c * 4, hv0);
      DOT4R(ah2r1, rWhh[2], c * 4, hv1);
    }
#define QRED(v)              \
  v += __shfl_xor(v, 1);     \
  v += __shfl_xor(v, 2)
    QRED(ai0r0); QRED(ai0r1); QRED(ai1r0); QRED(ai1r1);
    QRED(ai2r0); QRED(ai2r1); QRED(ah0r0); QRED(ah0r1);
    QRED(ah1r0); QRED(ah1r1); QRED(ah2r0); QRED(ah2r1);

    float hg[2], hh[2];
    {
      const float rg0 = fsig(ai0r0 + ah0r0 + rB0);
      const float zg0 = fsig(ai1r0 + ah1r0 + rB1);
      const float nn0 = ftanh_fast(ai2r0 + rBi2 + rg0 * (ah2r0 + rBh2));
      hg[0] = (1.0f - zg0) * nn0 + zg0 * h2e[0];
      const float rg1 = fsig(ai0r1 + ah0r1 + rB0);
      const float zg1 = fsig(ai1r1 + ah1r1 + rB1);
      const float nn1 = ftanh_fast(ai2r1 + rBi2 + rg1 * (ah2r1 + rBh2));
      hg[1] = (1.0f - zg1) * nn1 + zg1 * h2e[1];
    }
    hh[0] = hg[0];
    hh[1] = hg[1];
    if (kq < 2) sH[kq][oq] = (f16)hg[kq];
    __syncthreads();  // B

    const float dt = sDt[i];
    const float sq = sSq[i];
    const float* zrow = &sZ[i * NSUB * 2];
    for (int s = 0; s < NSUB; ++s) {
      // L1
      float a0 = 0.f, a1 = 0.f;
#pragma unroll
      for (int c = 0; c < 4; ++c) {
        const uint4 hv0 = *(const uint4*)&sH[0][kb32 + c * 8];
        const uint4 hv1 = *(const uint4*)&sH[1][kb32 + c * 8];
        DOT4R(a0, rW1, c * 4, hv0);
        DOT4R(a1, rW1, c * 4, hv1);
      }
      QRED(a0);
      QRED(a1);
      const float av0 = a0 + bias1;
      const float av1 = a1 + bias1;
      const float act0 = (oq < 64) ? ftanh_fast(av0) : fsoftplus(av0);
      const float act1 = (oq < 64) ? ftanh_fast(av1) : fsoftplus(av1);
      if (kq < 2) sAct[kq][oq] = (f16)(kq ? act1 : act0);
      __syncthreads();
      // L2
      float fa0 = 0.f, ga0 = 0.f, fa1 = 0.f, ga1 = 0.f;
#pragma unroll
      for (int c = 0; c < 2; ++c) {
        const uint4 tv0 = *(const uint4*)&sAct[0][kb16 + c * 8];
        const uint4 tv1 = *(const uint4*)&sAct[1][kb16 + c * 8];
        const uint4 sv0 = *(const uint4*)&sAct[0][64 + kb16 + c * 8];
        const uint4 sv1 = *(const uint4*)&sAct[1][64 + kb16 + c * 8];
        DOT4R(fa0, rW2d, c * 4, tv0);
        DOT4R(fa1, rW2d, c * 4, tv1);
        DOT4R(ga0, rW2g, c * 4, sv0);
        DOT4R(ga1, rW2g, c * 4, sv1);
      }
      QRED(fa0);
      QRED(fa1);
      QRED(ga0);
      QRED(ga1);
      const float z0 = zrow[s * 2 + 0];
      const float z1 = zrow[s * 2 + 1];
      hh[0] += (fa0 + bias2d) * dt + (ga0 + bias2g) * (sq * z0);
      hh[1] += (fa1 + bias2d) * dt + (ga1 + bias2g) * (sq * z1);
      if (kq < 2) sH[kq][oq] = (f16)hh[kq];
      __syncthreads();
    }
#undef QRED

    // ---- h1/h2 update (gated per row; frozen once row done)
    if (i < La) {
      h2e[0] = (i == 0) ? hg[0] : (sU[i] * hg[0] + (1.0f - sU[i]) * h1e[0]);
      h1e[0] = hh[0];
    }
    if (i < Lb) {
      h2e[1] = (i == 0) ? hg[1] : (sU[i] * hg[1] + (1.0f - sU[i]) * h1e[1]);
      h1e[1] = hh[1];
    }
    if (kq < 2) sH2[kq][oq] = (f16)h2e[kq];
  }

  if (kq < 2) out[(size_t)(b0 + kq) * H_LEN + oq] = h2e[kq];
}

extern "C" void kernel_launch(void* const* d_in, const int* in_sizes, int n_in,
                              void* d_out, int out_size, void* d_ws,
                              size_t ws_size, hipStream_t stream) {
  (void)in_sizes;
  (void)n_in;
  (void)out_size;
  (void)ws_size;
  const float* inputs = (const float*)d_in[0];
  const float* times = (const float*)d_in[1];
  const int* non_zero = (const int*)d_in[2];
  const float* Wih = (const float*)d_in[3];
  const float* Whh = (const float*)d_in[4];
  const float* bih = (const float*)d_in[5];
  const float* bhh = (const float*)d_in[6];
  const float* dW1 = (const float*)d_in[7];
  const float* db1 = (const float*)d_in[8];
  const float* dW2 = (const float*)d_in[9];
  const float* db2 = (const float*)d_in[10];
  const float* gW1 = (const float*)d_in[11];
  const float* gb1 = (const float*)d_in[12];
  const float* gW2 = (const float*)d_in[13];
  const float* gb2 = (const float*)d_in[14];
  float* out = (float*)d_out;
  float* wsTd = (float*)d_ws;

  hipLaunchKernelGGL(td_kernel, dim3(NSTEP), dim3(256), 0, stream, times,
                     non_zero, wsTd);
  hipLaunchKernelGGL(sde_fused_kernel, dim3(256), dim3(512), 0, stream, inputs,
                     non_zero, Wih, Whh, bih, bhh, dW1, db1, dW2, db2, gW1, gb1,
                     gW2, gb2, wsTd, out);
}